// Round 1
// baseline (192.766 us; speedup 1.0000x reference)
//
#include <hip/hip_runtime.h>

typedef unsigned short u16;
typedef __bf16 bf16x8 __attribute__((ext_vector_type(8)));
typedef float f32x4 __attribute__((ext_vector_type(4)));

struct alignas(16) V4 { unsigned x, y, z, w; };
union U16 { V4 v; u16 us[8]; };

// f32 -> bf16 RTNE (finite values only; all our data is finite)
__device__ __forceinline__ u16 f2b(float f) {
  unsigned u = __builtin_bit_cast(unsigned, f);
  u += 0x7FFFu + ((u >> 16) & 1u);
  return (u16)(u >> 16);
}
__device__ __forceinline__ bf16x8 asb(V4 v) { return __builtin_bit_cast(bf16x8, v); }
__device__ __forceinline__ V4 ldg16(const u16* p) { return *reinterpret_cast<const V4*>(p); }
__device__ __forceinline__ f32x4 mfma16(bf16x8 a, bf16x8 b, f32x4 c) {
  return __builtin_amdgcn_mfma_f32_16x16x32_bf16(a, b, c, 0, 0, 0);
}

// ---------------------------------------------------------------------------
// Prep: transpose+cast weights to bf16, cast descriptor to bf16.
// wqT/wkT/wvT: [512][64], wdT: [64][256], woT: [64][512], descb: [4096][256]
// ---------------------------------------------------------------------------
__global__ __launch_bounds__(256) void k_prep(
    const float* __restrict__ wq, const float* __restrict__ wk,
    const float* __restrict__ wv, const float* __restrict__ wd,
    const float* __restrict__ wo, const float* __restrict__ desc,
    u16* __restrict__ wqT, u16* __restrict__ wkT, u16* __restrict__ wvT,
    u16* __restrict__ wdT, u16* __restrict__ woT, u16* __restrict__ descb) {
  int i = blockIdx.x * 256 + threadIdx.x;
  if (i < 32768) {                                   // wqT[n][d] = wq[d][n]
    int n = i >> 6, d = i & 63;
    wqT[i] = f2b(wq[d * 512 + n]);
  } else if (i < 65536) {
    int j = i - 32768; int n = j >> 6, d = j & 63;
    wkT[j] = f2b(wk[d * 512 + n]);
  } else if (i < 98304) {
    int j = i - 65536; int n = j >> 6, d = j & 63;
    wvT[j] = f2b(wv[d * 512 + n]);
  } else if (i < 114688) {                           // wdT[e][v] = wd[v][e]
    int j = i - 98304; int e = j >> 8, v = j & 255;
    wdT[j] = f2b(wd[v * 64 + e]);
  } else if (i < 147456) {                           // woT[n][k] = wo[k][n]
    int j = i - 114688; int n = j >> 9, kk = j & 511;
    woT[j] = f2b(wo[kk * 64 + n]);
  } else if (i < 1196032) {
    int j = i - 147456;
    descb[j] = f2b(desc[j]);
  }
}

// ---------------------------------------------------------------------------
// Conv3d(P=4,stride=4) + LayerNorm + pos_emb -> vox_emb bf16 [16384][64]
// One wave per output row (patch); lane = output channel e.
// ---------------------------------------------------------------------------
__global__ __launch_bounds__(256) void k_convln(
    const float* __restrict__ vox, const float* __restrict__ cw,
    const float* __restrict__ cb, const float* __restrict__ lng,
    const float* __restrict__ lnb, const float* __restrict__ pos,
    u16* __restrict__ vox_emb) {
  __shared__ float wT[64 * 65];   // wT[v][e], stride 65 avoids bank conflicts
  __shared__ float pl[4][64];
  const int t = threadIdx.x;
  for (int i = t; i < 4096; i += 256) {
    int e = i >> 6, v = i & 63;
    wT[v * 65 + e] = cw[i];
  }
  const int w = t >> 6, lane = t & 63;
  const int row = blockIdx.x * 4 + w;       // [0, 16384)
  const int b = row >> 12, np = row & 4095;
  const int pd = np >> 8, ph = (np >> 4) & 15, pw = np & 15;
  const int i3 = lane >> 4, j3 = (lane >> 2) & 3, k3 = lane & 3;
  pl[w][lane] = vox[(size_t)b * 262144 + (size_t)(pd * 4 + i3) * 4096 +
                    (ph * 4 + j3) * 64 + (pw * 4 + k3)];
  __syncthreads();
  float acc = cb[lane];
  #pragma unroll
  for (int v = 0; v < 64; ++v) acc += pl[w][v] * wT[v * 65 + lane];
  // LayerNorm over 64 lanes (biased variance, matching jnp.var ddof=0)
  float s1 = acc, s2 = acc * acc;
  #pragma unroll
  for (int m = 1; m < 64; m <<= 1) { s1 += __shfl_xor(s1, m); s2 += __shfl_xor(s2, m); }
  const float mu = s1 * (1.0f / 64.0f);
  const float var = s2 * (1.0f / 64.0f) - mu * mu;
  const float rs = rsqrtf(var + 1e-5f);
  const float y = (acc - mu) * rs * lng[lane] + lnb[lane] + pos[np * 64 + lane];
  vox_emb[(size_t)row * 64 + lane] = f2b(y);
}

// ---------------------------------------------------------------------------
// des_emb = descb[4096][256] @ wd + bd -> bf16 [4096][64]
// MFMA: block = 4 waves x 16 rows.
// ---------------------------------------------------------------------------
__global__ __launch_bounds__(256) void k_des(
    const u16* __restrict__ descb, const u16* __restrict__ wdT,
    const float* __restrict__ bd, u16* __restrict__ desemb) {
  const int t = threadIdx.x, w = t >> 6, lane = t & 63, lr = lane & 15, lc = lane >> 4;
  const int row0 = blockIdx.x * 64 + w * 16;
  const u16* arow = descb + (size_t)(row0 + lr) * 256;
  const f32x4 z = {0.f, 0.f, 0.f, 0.f};
  f32x4 acc[4] = {z, z, z, z};
  for (int kc = 0; kc < 8; ++kc) {
    bf16x8 a = asb(ldg16(arow + kc * 32 + lc * 8));
    #pragma unroll
    for (int et = 0; et < 4; ++et) {
      bf16x8 bf = asb(ldg16(wdT + (size_t)(et * 16 + lr) * 256 + kc * 32 + lc * 8));
      acc[et] = mfma16(a, bf, acc[et]);
    }
  }
  #pragma unroll
  for (int et = 0; et < 4; ++et) {
    const int e = et * 16 + lr;
    const float be = bd[e];
    #pragma unroll
    for (int r = 0; r < 4; ++r)
      desemb[(size_t)(row0 + lc * 4 + r) * 64 + e] = f2b(acc[et][r] + be);
  }
}

// ---------------------------------------------------------------------------
// Q projection: q = vox_emb @ wq + bq -> qb bf16 [B*H][4096][64]
// plus aeq[b,h,np] = alpha*SCALE*exp(-|q|^2)
// ---------------------------------------------------------------------------
__global__ __launch_bounds__(256) void k_qproj(
    const u16* __restrict__ vox_emb, const u16* __restrict__ wqT,
    const float* __restrict__ bq, const float* __restrict__ alpha,
    u16* __restrict__ qb, float* __restrict__ aeq) {
  const int t = threadIdx.x, w = t >> 6, lane = t & 63, lr = lane & 15, lc = lane >> 4;
  const int row0 = blockIdx.x * 64 + w * 16;
  const int b = row0 >> 12;
  const u16* arow = vox_emb + (size_t)(row0 + lr) * 64;
  const bf16x8 a0 = asb(ldg16(arow + lc * 8));
  const bf16x8 a1 = asb(ldg16(arow + 32 + lc * 8));
  const float af = alpha[0] * 0.125f;
  float sq[4] = {0.f, 0.f, 0.f, 0.f};
  const f32x4 z = {0.f, 0.f, 0.f, 0.f};
  for (int et = 0; et < 32; ++et) {
    f32x4 acc = z;
    acc = mfma16(a0, asb(ldg16(wqT + (size_t)(et * 16 + lr) * 64 + lc * 8)), acc);
    acc = mfma16(a1, asb(ldg16(wqT + (size_t)(et * 16 + lr) * 64 + 32 + lc * 8)), acc);
    const int ef = et * 16 + lr;
    const float be = bq[ef];
    const int h = et >> 2, ein = (et & 3) * 16 + lr;
    #pragma unroll
    for (int r = 0; r < 4; ++r) {
      const float q = acc[r] + be;
      sq[r] += q * q;
      const int np = (row0 & 4095) + lc * 4 + r;
      qb[(((size_t)b * 8 + h) * 4096 + np) * 64 + ein] = f2b(q);
    }
    if ((et & 3) == 3) {
      #pragma unroll
      for (int r = 0; r < 4; ++r) {
        float s = sq[r];
        s += __shfl_xor(s, 1); s += __shfl_xor(s, 2);
        s += __shfl_xor(s, 4); s += __shfl_xor(s, 8);
        if (lr == 0) {
          const int np = (row0 & 4095) + lc * 4 + r;
          aeq[((size_t)b * 8 + h) * 4096 + np] = af * __expf(-s);
        }
        sq[r] = 0.f;
      }
    }
  }
}

// ---------------------------------------------------------------------------
// K/V projections from des_emb. kb bf16 [B*H][1024][64]; ek = exp(-|k|^2);
// vtb bf16 transposed [B*H][64][1024].
// ---------------------------------------------------------------------------
__global__ __launch_bounds__(256) void k_kvproj(
    const u16* __restrict__ desemb, const u16* __restrict__ wkT,
    const float* __restrict__ bk, const u16* __restrict__ wvT,
    const float* __restrict__ bv, u16* __restrict__ kb,
    float* __restrict__ ek, u16* __restrict__ vtb) {
  const int t = threadIdx.x, w = t >> 6, lane = t & 63, lr = lane & 15, lc = lane >> 4;
  const int row0 = blockIdx.x * 64 + w * 16;
  const int b = row0 >> 10;
  const u16* arow = desemb + (size_t)(row0 + lr) * 64;
  const bf16x8 a0 = asb(ldg16(arow + lc * 8));
  const bf16x8 a1 = asb(ldg16(arow + 32 + lc * 8));
  const f32x4 z = {0.f, 0.f, 0.f, 0.f};
  float sq[4] = {0.f, 0.f, 0.f, 0.f};
  for (int et = 0; et < 32; ++et) {                 // K pass
    f32x4 acc = z;
    acc = mfma16(a0, asb(ldg16(wkT + (size_t)(et * 16 + lr) * 64 + lc * 8)), acc);
    acc = mfma16(a1, asb(ldg16(wkT + (size_t)(et * 16 + lr) * 64 + 32 + lc * 8)), acc);
    const float be = bk[et * 16 + lr];
    const int h = et >> 2, ein = (et & 3) * 16 + lr;
    #pragma unroll
    for (int r = 0; r < 4; ++r) {
      const float kv = acc[r] + be;
      sq[r] += kv * kv;
      const int sd = (row0 & 1023) + lc * 4 + r;
      kb[(((size_t)b * 8 + h) * 1024 + sd) * 64 + ein] = f2b(kv);
    }
    if ((et & 3) == 3) {
      #pragma unroll
      for (int r = 0; r < 4; ++r) {
        float s = sq[r];
        s += __shfl_xor(s, 1); s += __shfl_xor(s, 2);
        s += __shfl_xor(s, 4); s += __shfl_xor(s, 8);
        if (lr == 0) {
          const int sd = (row0 & 1023) + lc * 4 + r;
          ek[((size_t)b * 8 + h) * 1024 + sd] = __expf(-s);
        }
        sq[r] = 0.f;
      }
    }
  }
  for (int et = 0; et < 32; ++et) {                 // V pass (store transposed)
    f32x4 acc = z;
    acc = mfma16(a0, asb(ldg16(wvT + (size_t)(et * 16 + lr) * 64 + lc * 8)), acc);
    acc = mfma16(a1, asb(ldg16(wvT + (size_t)(et * 16 + lr) * 64 + 32 + lc * 8)), acc);
    const float be = bv[et * 16 + lr];
    const int h = et >> 2, ein = (et & 3) * 16 + lr;
    #pragma unroll
    for (int r = 0; r < 4; ++r) {
      const float vv = acc[r] + be;
      const int sd = (row0 & 1023) + lc * 4 + r;
      vtb[(((size_t)b * 8 + h) * 64 + ein) * 1024 + sd] = f2b(vv);
    }
  }
}

// ---------------------------------------------------------------------------
// Fused L2 attention. Block: (q-tile 64 rows) x (b,h). 4 waves x 16 q-rows.
// logits x = aeq[q]*ek[k]*exp(2*q.k) in (0, 0.133] -> softmax without max.
// LDS strides are odd multiples of 16B => conflict-free ds_read_b128.
// ---------------------------------------------------------------------------
__global__ __launch_bounds__(256) void k_attn(
    const u16* __restrict__ qb, const u16* __restrict__ kb,
    const u16* __restrict__ vtb, const float* __restrict__ aeq,
    const float* __restrict__ ekg, u16* __restrict__ attn) {
  __shared__ V4 Kl[128 * 9];      // K tile: 128 rows, 8 V4 + 1 pad
  __shared__ V4 Vl[64 * 17];      // V^T tile: 64 e-rows, 16 V4 + 1 pad
  __shared__ U16 Pl[4][80];       // per-wave P tile 16x32 bf16, 5 V4/row
  const int t = threadIdx.x, w = t >> 6, lane = t & 63, lr = lane & 15, lc = lane >> 4;
  const int bh = blockIdx.y, q0 = blockIdx.x * 64;
  const int b = bh >> 3, h = bh & 7;

  const u16* qrow = qb + ((size_t)bh * 4096 + q0 + w * 16 + lr) * 64;
  const bf16x8 qf0 = asb(ldg16(qrow + lc * 8));
  const bf16x8 qf1 = asb(ldg16(qrow + 32 + lc * 8));
  float aeqv[4];
  #pragma unroll
  for (int r = 0; r < 4; ++r)
    aeqv[r] = aeq[(size_t)bh * 4096 + q0 + w * 16 + lc * 4 + r];

  const V4* kb4 = reinterpret_cast<const V4*>(kb) + (size_t)bh * 1024 * 8;
  const V4* vt4 = reinterpret_cast<const V4*>(vtb) + (size_t)bh * 64 * 128;
  const float* ekh = ekg + (size_t)bh * 1024;

  const f32x4 z = {0.f, 0.f, 0.f, 0.f};
  f32x4 o0 = z, o1 = z, o2 = z, o3 = z;
  float dn[4] = {0.f, 0.f, 0.f, 0.f};

  const int rowk = t >> 1, halfk = t & 1;
  const int rowe = t >> 2, qv = t & 3;

  for (int kt = 0; kt < 8; ++kt) {
    // stage K tile (128x64 bf16) and V^T tile (64x128 bf16)
    {
      const V4* ks = kb4 + (size_t)(kt * 128 + rowk) * 8 + halfk * 4;
      V4* kd = Kl + rowk * 9 + halfk * 4;
      #pragma unroll
      for (int i = 0; i < 4; ++i) kd[i] = ks[i];
      const V4* vs = vt4 + (size_t)rowe * 128 + kt * 16 + qv * 4;
      V4* vd = Vl + rowe * 17 + qv * 4;
      #pragma unroll
      for (int i = 0; i < 4; ++i) vd[i] = vs[i];
    }
    __syncthreads();

    #pragma unroll
    for (int c2 = 0; c2 < 4; ++c2) {
      const int kb32 = c2 * 32;
      f32x4 s0 = z, s1 = z;
      {
        const V4* kr0 = Kl + (kb32 + lr) * 9;
        s0 = mfma16(qf0, asb(kr0[lc]), s0);
        s0 = mfma16(qf1, asb(kr0[4 + lc]), s0);
        const V4* kr1 = Kl + (kb32 + 16 + lr) * 9;
        s1 = mfma16(qf0, asb(kr1[lc]), s1);
        s1 = mfma16(qf1, asb(kr1[4 + lc]), s1);
      }
      const float e0 = ekh[kt * 128 + kb32 + lr];
      const float e1 = ekh[kt * 128 + kb32 + 16 + lr];
      #pragma unroll
      for (int r = 0; r < 4; ++r) {
        const float p0 = __expf(aeqv[r] * e0 * __expf(2.0f * s0[r]));
        const float p1 = __expf(aeqv[r] * e1 * __expf(2.0f * s1[r]));
        dn[r] += p0 + p1;
        Pl[w][(lc * 4 + r) * 5 + (lr >> 3)].us[lr & 7] = f2b(p0);
        Pl[w][(lc * 4 + r) * 5 + 2 + (lr >> 3)].us[lr & 7] = f2b(p1);
      }
      const bf16x8 pf = asb(Pl[w][lr * 5 + lc].v);
      o0 = mfma16(pf, asb(Vl[(lr) * 17 + c2 * 4 + lc]), o0);
      o1 = mfma16(pf, asb(Vl[(16 + lr) * 17 + c2 * 4 + lc]), o1);
      o2 = mfma16(pf, asb(Vl[(32 + lr) * 17 + c2 * 4 + lc]), o2);
      o3 = mfma16(pf, asb(Vl[(48 + lr) * 17 + c2 * 4 + lc]), o3);
    }
    __syncthreads();
  }

  #pragma unroll
  for (int r = 0; r < 4; ++r) {
    float s = dn[r];
    s += __shfl_xor(s, 1); s += __shfl_xor(s, 2);
    s += __shfl_xor(s, 4); s += __shfl_xor(s, 8);
    dn[r] = 1.0f / s;
  }
  u16* orow = attn + ((size_t)b * 4096 + q0 + w * 16) * 512 + h * 64;
  #pragma unroll
  for (int r = 0; r < 4; ++r) {
    const size_t rw = (size_t)(lc * 4 + r) * 512;
    orow[rw + lr]      = f2b(o0[r] * dn[r]);
    orow[rw + 16 + lr] = f2b(o1[r] * dn[r]);
    orow[rw + 32 + lr] = f2b(o2[r] * dn[r]);
    orow[rw + 48 + lr] = f2b(o3[r] * dn[r]);
  }
}

// ---------------------------------------------------------------------------
// out = attn[16384][512] @ wo + bo -> fp32 [16384][64]
// ---------------------------------------------------------------------------
__global__ __launch_bounds__(256) void k_out(
    const u16* __restrict__ attn, const u16* __restrict__ woT,
    const float* __restrict__ bo, float* __restrict__ out) {
  const int t = threadIdx.x, w = t >> 6, lane = t & 63, lr = lane & 15, lc = lane >> 4;
  const int row0 = blockIdx.x * 64 + w * 16;
  const V4* arow = reinterpret_cast<const V4*>(attn + (size_t)(row0 + lr) * 512);
  const f32x4 z = {0.f, 0.f, 0.f, 0.f};
  f32x4 acc[4] = {z, z, z, z};
  for (int kc = 0; kc < 16; ++kc) {
    const bf16x8 a = asb(arow[kc * 4 + lc]);
    #pragma unroll
    for (int et = 0; et < 4; ++et) {
      const V4* brow = reinterpret_cast<const V4*>(woT + (size_t)(et * 16 + lr) * 512);
      acc[et] = mfma16(a, asb(brow[kc * 4 + lc]), acc[et]);
    }
  }
  #pragma unroll
  for (int et = 0; et < 4; ++et) {
    const float be = bo[et * 16 + lr];
    #pragma unroll
    for (int r = 0; r < 4; ++r)
      out[(size_t)(row0 + lc * 4 + r) * 64 + et * 16 + lr] = acc[et][r] + be;
  }
}

// ---------------------------------------------------------------------------
extern "C" void kernel_launch(void* const* d_in, const int* in_sizes, int n_in,
                              void* d_out, int out_size, void* d_ws, size_t ws_size,
                              hipStream_t stream) {
  (void)in_sizes; (void)n_in; (void)out_size; (void)ws_size;
  const float* vox   = (const float*)d_in[0];
  const float* desc  = (const float*)d_in[1];
  const float* cw    = (const float*)d_in[2];
  const float* cb    = (const float*)d_in[3];
  const float* lng   = (const float*)d_in[4];
  const float* lnb   = (const float*)d_in[5];
  const float* pos   = (const float*)d_in[6];
  const float* wq    = (const float*)d_in[7];
  const float* bq    = (const float*)d_in[8];
  const float* wk    = (const float*)d_in[9];
  const float* bk    = (const float*)d_in[10];
  const float* wv    = (const float*)d_in[11];
  const float* bv    = (const float*)d_in[12];
  const float* wd    = (const float*)d_in[13];
  const float* bd    = (const float*)d_in[14];
  const float* alpha = (const float*)d_in[15];
  const float* wo    = (const float*)d_in[16];
  const float* bo    = (const float*)d_in[17];
  float* out = (float*)d_out;

  char* ws = (char*)d_ws;
  size_t off = 0;
  auto alloc = [&](size_t bytes) {
    char* p = ws + off;
    off += (bytes + 255) & ~(size_t)255;
    return p;
  };
  u16*   vox_emb = (u16*)alloc((size_t)16384 * 64 * 2);
  u16*   descb   = (u16*)alloc((size_t)4096 * 256 * 2);
  u16*   desemb  = (u16*)alloc((size_t)4096 * 64 * 2);
  u16*   qb      = (u16*)alloc((size_t)16384 * 512 * 2);
  u16*   kb      = (u16*)alloc((size_t)4096 * 512 * 2);
  u16*   vtb     = (u16*)alloc((size_t)4096 * 512 * 2);
  float* aeq     = (float*)alloc((size_t)131072 * 4);
  float* ek      = (float*)alloc((size_t)32768 * 4);
  u16*   attn    = (u16*)alloc((size_t)16384 * 512 * 2);
  u16*   wqT     = (u16*)alloc((size_t)32768 * 2);
  u16*   wkT     = (u16*)alloc((size_t)32768 * 2);
  u16*   wvT     = (u16*)alloc((size_t)32768 * 2);
  u16*   wdT     = (u16*)alloc((size_t)16384 * 2);
  u16*   woT     = (u16*)alloc((size_t)32768 * 2);

  k_prep<<<4672, 256, 0, stream>>>(wq, wk, wv, wd, wo, desc, wqT, wkT, wvT, wdT, woT, descb);
  k_convln<<<4096, 256, 0, stream>>>(vox, cw, cb, lng, lnb, pos, vox_emb);
  k_des<<<64, 256, 0, stream>>>(descb, wdT, bd, desemb);
  k_qproj<<<256, 256, 0, stream>>>(vox_emb, wqT, bq, alpha, qb, aeq);
  k_kvproj<<<64, 256, 0, stream>>>(desemb, wkT, bk, wvT, bv, kb, ek, vtb);
  k_attn<<<dim3(64, 32), 256, 0, stream>>>(qb, kb, vtb, aeq, ek, attn);
  k_out<<<256, 256, 0, stream>>>(attn, woT, bo, out);
}

// Round 4
// 161.486 us; speedup vs baseline: 1.1937x; 1.1937x over previous
//
#include <hip/hip_runtime.h>

typedef unsigned short u16;
typedef __bf16 bf16x8 __attribute__((ext_vector_type(8)));
typedef float f32x4 __attribute__((ext_vector_type(4)));

struct alignas(16) V4 { unsigned x, y, z, w; };
struct alignas(8)  V2 { unsigned x, y; };

// f32 -> bf16 RTNE (bit-twiddle; HW-verified in R1)
__device__ __forceinline__ u16 f2b(float f) {
  unsigned u = __builtin_bit_cast(unsigned, f);
  u += 0x7FFFu + ((u >> 16) & 1u);
  return (u16)(u >> 16);
}
// RTNE pack of two f32 -> u32 (lo = a, hi = b)
__device__ __forceinline__ unsigned pk2(float a, float b) {
  return (unsigned)f2b(a) | ((unsigned)f2b(b) << 16);
}
__device__ __forceinline__ bf16x8 asb(V4 v) { return __builtin_bit_cast(bf16x8, v); }
__device__ __forceinline__ bf16x8 mk8(unsigned a, unsigned b, unsigned c, unsigned d) {
  V4 v; v.x = a; v.y = b; v.z = c; v.w = d; return asb(v);
}
__device__ __forceinline__ V4 ldg16(const u16* p) { return *reinterpret_cast<const V4*>(p); }
__device__ __forceinline__ f32x4 mfma16(bf16x8 a, bf16x8 b, f32x4 c) {
  return __builtin_amdgcn_mfma_f32_16x16x32_bf16(a, b, c, 0, 0, 0);
}
// LDS fragment, split k-map: 8B at base+off, 8B at base+off+32.
// Valid because the same (lane,reg)->k assignment is used on both operands.
__device__ __forceinline__ bf16x8 ldfrag(const char* base, int off) {
  V2 lo = *reinterpret_cast<const V2*>(base + off);
  V2 hi = *reinterpret_cast<const V2*>(base + off + 32);
  return mk8(lo.x, lo.y, hi.x, hi.y);
}

// ---------------------------------------------------------------------------
// Prep: transpose+cast weights to bf16, cast descriptor to bf16.
// ---------------------------------------------------------------------------
__global__ __launch_bounds__(256) void k_prep(
    const float* __restrict__ wq, const float* __restrict__ wk,
    const float* __restrict__ wv, const float* __restrict__ wd,
    const float* __restrict__ wo, const float* __restrict__ desc,
    u16* __restrict__ wqT, u16* __restrict__ wkT, u16* __restrict__ wvT,
    u16* __restrict__ wdT, u16* __restrict__ woT, u16* __restrict__ descb) {
  int i = blockIdx.x * 256 + threadIdx.x;
  if (i < 32768) {                                   // wqT[n][d] = wq[d][n]
    int n = i >> 6, d = i & 63;
    wqT[i] = f2b(wq[d * 512 + n]);
  } else if (i < 65536) {
    int j = i - 32768; int n = j >> 6, d = j & 63;
    wkT[j] = f2b(wk[d * 512 + n]);
  } else if (i < 98304) {
    int j = i - 65536; int n = j >> 6, d = j & 63;
    wvT[j] = f2b(wv[d * 512 + n]);
  } else if (i < 114688) {                           // wdT[e][v] = wd[v][e]
    int j = i - 98304; int e = j >> 8, v = j & 255;
    wdT[j] = f2b(wd[v * 64 + e]);
  } else if (i < 147456) {                           // woT[n][k] = wo[k][n]
    int j = i - 114688; int n = j >> 9, kk = j & 511;
    woT[j] = f2b(wo[kk * 64 + n]);
  } else if (i < 409600) {                           // descb, 4 elems/thread
    int j = (i - 147456) * 4;
    const f32x4 dv = *reinterpret_cast<const f32x4*>(desc + j);
    uint2 pw; pw.x = pk2(dv[0], dv[1]); pw.y = pk2(dv[2], dv[3]);
    *reinterpret_cast<uint2*>(descb + j) = pw;
  }
}

// ---------------------------------------------------------------------------
// Conv3d(P=4,stride=4) + LayerNorm + pos_emb -> vox_emb bf16 [16384][64]
// ---------------------------------------------------------------------------
__global__ __launch_bounds__(256) void k_convln(
    const float* __restrict__ vox, const float* __restrict__ cw,
    const float* __restrict__ cb, const float* __restrict__ lng,
    const float* __restrict__ lnb, const float* __restrict__ pos,
    u16* __restrict__ vox_emb) {
  __shared__ float wT[64 * 65];
  __shared__ float pl[4][64];
  const int t = threadIdx.x;
  for (int i = t; i < 4096; i += 256) wT[(i & 63) * 65 + (i >> 6)] = cw[i];
  const int w = t >> 6, lane = t & 63;
  const float cbl = cb[lane], lg = lng[lane], lb = lnb[lane];
  const int i3 = lane >> 4, j3 = (lane >> 2) & 3, k3 = lane & 3;
  for (int i = 0; i < 8; ++i) {
    const int row = blockIdx.x * 32 + w * 8 + i;
    const int b = row >> 12, np = row & 4095;
    const int pd = np >> 8, ph = (np >> 4) & 15, pw = np & 15;
    __syncthreads();
    pl[w][lane] = vox[(size_t)b * 262144 + (size_t)(pd * 4 + i3) * 4096 +
                      (ph * 4 + j3) * 64 + (pw * 4 + k3)];
    __syncthreads();
    float acc = cbl;
    #pragma unroll
    for (int v = 0; v < 64; ++v) acc += pl[w][v] * wT[v * 65 + lane];
    float s1 = acc, s2 = acc * acc;
    #pragma unroll
    for (int m = 1; m < 64; m <<= 1) { s1 += __shfl_xor(s1, m); s2 += __shfl_xor(s2, m); }
    const float mu = s1 * (1.0f / 64.0f);
    const float var = s2 * (1.0f / 64.0f) - mu * mu;
    const float y = (acc - mu) * rsqrtf(var + 1e-5f) * lg + lb + pos[np * 64 + lane];
    vox_emb[(size_t)row * 64 + lane] = f2b(y);
  }
}

// ---------------------------------------------------------------------------
// des_emb = descb[4096][256] @ wd + bd -> bf16 [4096][64]
// ---------------------------------------------------------------------------
__global__ __launch_bounds__(64) void k_des(
    const u16* __restrict__ descb, const u16* __restrict__ wdT,
    const float* __restrict__ bd, u16* __restrict__ desemb) {
  const int lane = threadIdx.x, lr = lane & 15, lc = lane >> 4;
  const int sd0 = blockIdx.x * 16;
  bf16x8 db[8];
  #pragma unroll
  for (int kc = 0; kc < 8; ++kc)
    db[kc] = asb(ldg16(descb + (size_t)(sd0 + lr) * 256 + kc * 32 + lc * 8));
  #pragma unroll
  for (int et = 0; et < 4; ++et) {
    f32x4 acc = {0.f, 0.f, 0.f, 0.f};
    #pragma unroll
    for (int kc = 0; kc < 8; ++kc) {
      const bf16x8 wa = asb(ldg16(wdT + (size_t)(et * 16 + lr) * 256 + kc * 32 + lc * 8));
      acc = mfma16(wa, db[kc], acc);
    }
    const f32x4 bdv = *reinterpret_cast<const f32x4*>(bd + et * 16 + lc * 4);
    uint2 pw;
    pw.x = pk2(acc[0] + bdv[0], acc[1] + bdv[1]);
    pw.y = pk2(acc[2] + bdv[2], acc[3] + bdv[3]);
    *reinterpret_cast<uint2*>(desemb + (size_t)(sd0 + lr) * 64 + et * 16 + lc * 4) = pw;
  }
}

// ---------------------------------------------------------------------------
// K/V projections. kb bf16 [bh][1024][64]; ek = exp(-|k|^2) f32;
// vtb bf16 transposed [bh][64][1024].
// ---------------------------------------------------------------------------
__global__ __launch_bounds__(64) void k_kvproj(
    const u16* __restrict__ desemb, const u16* __restrict__ wkT,
    const float* __restrict__ bk, const u16* __restrict__ wvT,
    const float* __restrict__ bv, u16* __restrict__ kb,
    float* __restrict__ ek, u16* __restrict__ vtb) {
  const int lane = threadIdx.x, lr = lane & 15, lc = lane >> 4;
  const int x = blockIdx.x, half = blockIdx.y;
  const int b = x >> 6, sd0 = (x & 63) * 16;
  const u16* drow = desemb + (size_t)(x * 16 + lr) * 64;
  const bf16x8 da0 = asb(ldg16(drow + lc * 8));
  const bf16x8 da1 = asb(ldg16(drow + 32 + lc * 8));
  float sq = 0.f;
  #pragma unroll
  for (int et = 0; et < 16; ++et) {                 // K pass (flipped)
    const int etg = half * 16 + et;
    const u16* wrow = wkT + (size_t)(etg * 16 + lr) * 64;
    f32x4 acc = {0.f, 0.f, 0.f, 0.f};
    acc = mfma16(asb(ldg16(wrow + lc * 8)), da0, acc);
    acc = mfma16(asb(ldg16(wrow + 32 + lc * 8)), da1, acc);
    const f32x4 bkv = *reinterpret_cast<const f32x4*>(bk + etg * 16 + lc * 4);
    const float k0 = acc[0] + bkv[0], k1 = acc[1] + bkv[1];
    const float k2 = acc[2] + bkv[2], k3 = acc[3] + bkv[3];
    sq += k0 * k0 + k1 * k1 + k2 * k2 + k3 * k3;
    const int h = etg >> 2;
    uint2 pw; pw.x = pk2(k0, k1); pw.y = pk2(k2, k3);
    *reinterpret_cast<uint2*>(kb + ((size_t)(b * 8 + h) * 1024 + sd0 + lr) * 64 +
                              (etg & 3) * 16 + lc * 4) = pw;
    if ((etg & 3) == 3) {
      float s = sq;
      s += __shfl_xor(s, 16); s += __shfl_xor(s, 32);
      if (lc == 0) ek[(size_t)(b * 8 + h) * 1024 + sd0 + lr] = __expf(-s);
      sq = 0.f;
    }
  }
  #pragma unroll
  for (int et = 0; et < 16; ++et) {                 // V pass
    const int etg = half * 16 + et;
    const u16* wrow = wvT + (size_t)(etg * 16 + lr) * 64;
    f32x4 acc = {0.f, 0.f, 0.f, 0.f};
    acc = mfma16(da0, asb(ldg16(wrow + lc * 8)), acc);
    acc = mfma16(da1, asb(ldg16(wrow + 32 + lc * 8)), acc);
    const float bvs = bv[etg * 16 + lr];
    const int h = etg >> 2;
    uint2 pw;
    pw.x = pk2(acc[0] + bvs, acc[1] + bvs);
    pw.y = pk2(acc[2] + bvs, acc[3] + bvs);
    *reinterpret_cast<uint2*>(vtb + ((size_t)(b * 8 + h) * 64 + (etg & 3) * 16 + lr) * 1024 +
                              sd0 + lc * 4) = pw;
  }
}

// ---------------------------------------------------------------------------
// Fused Q-projection + L2 attention. R1-exact arithmetic:
//   q bf16 = f2b(q) unscaled; p = __expf(aeq * ek * __expf(2*q.k));
//   P packed via f2b; denominator = fp32 VALU sum (reduced over lc).
// Block: 4 waves x 64 q-rows. grid (16, 32).
// ---------------------------------------------------------------------------
__global__ __launch_bounds__(256) void k_attn(
    const u16* __restrict__ vox_emb, const u16* __restrict__ wqT,
    const float* __restrict__ bq, const float* __restrict__ alpha,
    const u16* __restrict__ kb, const float* __restrict__ ekg,
    const u16* __restrict__ vtb, u16* __restrict__ attn) {
  __shared__ __align__(16) char Kl[128 * 144];   // K tile: 128 x 64 bf16, 144B stride
  __shared__ __align__(16) char Vl[64 * 272];    // V^T tile: 64 x 128 bf16, 272B stride
  const int t = threadIdx.x, w = t >> 6, lane = t & 63, lr = lane & 15, lc = lane >> 4;
  const int bh = blockIdx.y, b = bh >> 3, h = bh & 7;
  const int q0 = blockIdx.x * 256 + w * 64;   // this wave's 64 q rows

  // ---- Q: q = vox_emb @ wq + bq; fragments hold f2b(q) (unscaled, R1-exact)
  bf16x8 qf0[4], qf1[4];
  float av[4];
  {
    bf16x8 vb0[4], vb1[4];
    #pragma unroll
    for (int g = 0; g < 4; ++g) {
      const u16* vrow = vox_emb + (size_t)(b * 4096 + q0 + g * 16 + lr) * 64;
      vb0[g] = asb(ldg16(vrow + lc * 8));
      vb1[g] = asb(ldg16(vrow + 32 + lc * 8));
    }
    float sq[4] = {0.f, 0.f, 0.f, 0.f};
    unsigned qd[4][4][2];
    #pragma unroll
    for (int et = 0; et < 4; ++et) {
      const u16* wrow = wqT + (size_t)((h * 4 + et) * 16 + lr) * 64;
      const bf16x8 wa0 = asb(ldg16(wrow + lc * 8));
      const bf16x8 wa1 = asb(ldg16(wrow + 32 + lc * 8));
      const f32x4 bqv = *reinterpret_cast<const f32x4*>(bq + (h * 4 + et) * 16 + lc * 4);
      #pragma unroll
      for (int g = 0; g < 4; ++g) {
        f32x4 acc = {0.f, 0.f, 0.f, 0.f};
        acc = mfma16(wa0, vb0[g], acc);
        acc = mfma16(wa1, vb1[g], acc);
        const float v0 = acc[0] + bqv[0], v1 = acc[1] + bqv[1];
        const float v2 = acc[2] + bqv[2], v3 = acc[3] + bqv[3];
        sq[g] += v0 * v0 + v1 * v1 + v2 * v2 + v3 * v3;
        qd[g][et][0] = pk2(v0, v1);
        qd[g][et][1] = pk2(v2, v3);
      }
    }
    const float ca = 0.125f * alpha[0];
    #pragma unroll
    for (int g = 0; g < 4; ++g) {
      float s = sq[g];
      s += __shfl_xor(s, 16); s += __shfl_xor(s, 32);
      av[g] = ca * __expf(-s);      // alpha*SCALE*exp(-|q|^2), fp32 q (R1-exact)
      qf0[g] = mk8(qd[g][0][0], qd[g][0][1], qd[g][1][0], qd[g][1][1]);
      qf1[g] = mk8(qd[g][2][0], qd[g][2][1], qd[g][3][0], qd[g][3][1]);
    }
  }

  const f32x4 z = {0.f, 0.f, 0.f, 0.f};
  f32x4 o[4][4];
  float dn[4] = {0.f, 0.f, 0.f, 0.f};
  #pragma unroll
  for (int g = 0; g < 4; ++g)
    #pragma unroll
    for (int m = 0; m < 4; ++m) o[g][m] = z;

  const V4* kb4 = reinterpret_cast<const V4*>(kb) + (size_t)bh * 1024 * 8;
  const V4* vt4 = reinterpret_cast<const V4*>(vtb) + (size_t)bh * 64 * 128;
  const float* ekh = ekg + (size_t)bh * 1024;

  for (int kt = 0; kt < 8; ++kt) {
    {  // stage K (128x64) and V^T (64x128) tiles
      const int rk = t >> 1, hk = (t & 1) * 4;
      const V4* ks = kb4 + (size_t)(kt * 128 + rk) * 8 + hk;
      V4* kd = reinterpret_cast<V4*>(Kl + rk * 144 + hk * 16);
      kd[0] = ks[0]; kd[1] = ks[1]; kd[2] = ks[2]; kd[3] = ks[3];
      const int re = t >> 2, hv = (t & 3) * 4;
      const V4* vs = vt4 + (size_t)re * 128 + kt * 16 + hv;
      V4* vd = reinterpret_cast<V4*>(Vl + re * 272 + hv * 16);
      vd[0] = vs[0]; vd[1] = vs[1]; vd[2] = vs[2]; vd[3] = vs[3];
    }
    __syncthreads();
    #pragma unroll
    for (int c2 = 0; c2 < 4; ++c2) {
      const char* kr0 = Kl + (c2 * 32 + lr) * 144 + lc * 8;
      const char* kr1 = kr0 + 16 * 144;
      const bf16x8 ka00 = ldfrag(kr0, 0),  ka01 = ldfrag(kr0, 64);
      const bf16x8 ka10 = ldfrag(kr1, 0),  ka11 = ldfrag(kr1, 64);
      const char* vrb = Vl + lr * 272 + c2 * 64 + lc * 8;
      const bf16x8 va0 = ldfrag(vrb, 0);
      const bf16x8 va1 = ldfrag(vrb + 16 * 272, 0);
      const bf16x8 va2 = ldfrag(vrb + 32 * 272, 0);
      const bf16x8 va3 = ldfrag(vrb + 48 * 272, 0);
      const f32x4 e0v = *reinterpret_cast<const f32x4*>(ekh + kt * 128 + c2 * 32 + lc * 4);
      const f32x4 e1v = *reinterpret_cast<const f32x4*>(ekh + kt * 128 + c2 * 32 + 16 + lc * 4);
      #pragma unroll
      for (int g = 0; g < 4; ++g) {
        f32x4 s0 = z, s1 = z;
        s0 = mfma16(ka00, qf0[g], s0); s0 = mfma16(ka01, qf1[g], s0);
        s1 = mfma16(ka10, qf0[g], s1); s1 = mfma16(ka11, qf1[g], s1);
        // R1-exact: p = expf(aeq * ek * expf(2*q.k))
        const float p00 = __expf(av[g] * e0v[0] * __expf(2.0f * s0[0]));
        const float p01 = __expf(av[g] * e0v[1] * __expf(2.0f * s0[1]));
        const float p02 = __expf(av[g] * e0v[2] * __expf(2.0f * s0[2]));
        const float p03 = __expf(av[g] * e0v[3] * __expf(2.0f * s0[3]));
        const float p10 = __expf(av[g] * e1v[0] * __expf(2.0f * s1[0]));
        const float p11 = __expf(av[g] * e1v[1] * __expf(2.0f * s1[1]));
        const float p12 = __expf(av[g] * e1v[2] * __expf(2.0f * s1[2]));
        const float p13 = __expf(av[g] * e1v[3] * __expf(2.0f * s1[3]));
        dn[g] += ((p00 + p01) + (p02 + p03)) + ((p10 + p11) + (p12 + p13));
        const bf16x8 pf = mk8(pk2(p00, p01), pk2(p02, p03),
                              pk2(p10, p11), pk2(p12, p13));
        o[g][0] = mfma16(va0, pf, o[g][0]);
        o[g][1] = mfma16(va1, pf, o[g][1]);
        o[g][2] = mfma16(va2, pf, o[g][2]);
        o[g][3] = mfma16(va3, pf, o[g][3]);
      }
    }
    __syncthreads();
  }

  u16* obase = attn + (size_t)(b * 4096 + q0 + lr) * 512 + h * 64 + lc * 4;
  #pragma unroll
  for (int g = 0; g < 4; ++g) {
    float s = dn[g];
    s += __shfl_xor(s, 16); s += __shfl_xor(s, 32);   // sum lane's k-subsets over lc
    const float inv = 1.0f / s;
    #pragma unroll
    for (int m = 0; m < 4; ++m) {
      uint2 pw;
      pw.x = pk2(o[g][m][0] * inv, o[g][m][1] * inv);
      pw.y = pk2(o[g][m][2] * inv, o[g][m][3] * inv);
      *reinterpret_cast<uint2*>(obase + (size_t)g * 16 * 512 + m * 16) = pw;
    }
  }
}

// ---------------------------------------------------------------------------
// out = attn[16384][512] @ wo + bo -> fp32 [16384][64]
// ---------------------------------------------------------------------------
__global__ __launch_bounds__(64) void k_out(
    const u16* __restrict__ attn, const u16* __restrict__ woT,
    const float* __restrict__ bo, float* __restrict__ out) {
  const int lane = threadIdx.x, lr = lane & 15, lc = lane >> 4;
  const int np0 = blockIdx.x * 16;
  const u16* arow = attn + (size_t)(np0 + lr) * 512;
  f32x4 acc[4] = {{0.f,0.f,0.f,0.f},{0.f,0.f,0.f,0.f},{0.f,0.f,0.f,0.f},{0.f,0.f,0.f,0.f}};
  #pragma unroll
  for (int kc = 0; kc < 16; ++kc) {
    const bf16x8 bfr = asb(ldg16(arow + kc * 32 + lc * 8));
    #pragma unroll
    for (int et = 0; et < 4; ++et) {
      const bf16x8 wa = asb(ldg16(woT + (size_t)(et * 16 + lr) * 512 + kc * 32 + lc * 8));
      acc[et] = mfma16(wa, bfr, acc[et]);
    }
  }
  #pragma unroll
  for (int et = 0; et < 4; ++et) {
    const f32x4 bov = *reinterpret_cast<const f32x4*>(bo + et * 16 + lc * 4);
    const f32x4 r = acc[et] + bov;
    *reinterpret_cast<f32x4*>(out + (size_t)(np0 + lr) * 64 + et * 16 + lc * 4) = r;
  }
}

// ---------------------------------------------------------------------------
extern "C" void kernel_launch(void* const* d_in, const int* in_sizes, int n_in,
                              void* d_out, int out_size, void* d_ws, size_t ws_size,
                              hipStream_t stream) {
  (void)in_sizes; (void)n_in; (void)out_size; (void)ws_size;
  const float* vox   = (const float*)d_in[0];
  const float* desc  = (const float*)d_in[1];
  const float* cw    = (const float*)d_in[2];
  const float* cb    = (const float*)d_in[3];
  const float* lng   = (const float*)d_in[4];
  const float* lnb   = (const float*)d_in[5];
  const float* pos   = (const float*)d_in[6];
  const float* wq    = (const float*)d_in[7];
  const float* bq    = (const float*)d_in[8];
  const float* wk    = (const float*)d_in[9];
  const float* bk    = (const float*)d_in[10];
  const float* wv    = (const float*)d_in[11];
  const float* bv    = (const float*)d_in[12];
  const float* wd    = (const float*)d_in[13];
  const float* bd    = (const float*)d_in[14];
  const float* alpha = (const float*)d_in[15];
  const float* wo    = (const float*)d_in[16];
  const float* bo    = (const float*)d_in[17];
  float* out = (float*)d_out;

  char* ws = (char*)d_ws;
  size_t off = 0;
  auto alloc = [&](size_t bytes) {
    char* p = ws + off;
    off += (bytes + 255) & ~(size_t)255;
    return p;
  };
  u16*   vox_emb = (u16*)alloc((size_t)16384 * 64 * 2);
  u16*   descb   = (u16*)alloc((size_t)4096 * 256 * 2);
  u16*   desemb  = (u16*)alloc((size_t)4096 * 64 * 2);
  u16*   kb      = (u16*)alloc((size_t)4096 * 512 * 2);
  u16*   vtb     = (u16*)alloc((size_t)4096 * 512 * 2);
  float* ek      = (float*)alloc((size_t)32768 * 4);
  u16*   attn    = (u16*)alloc((size_t)16384 * 512 * 2);
  u16*   wqT     = (u16*)alloc((size_t)32768 * 2);
  u16*   wkT     = (u16*)alloc((size_t)32768 * 2);
  u16*   wvT     = (u16*)alloc((size_t)32768 * 2);
  u16*   wdT     = (u16*)alloc((size_t)16384 * 2);
  u16*   woT     = (u16*)alloc((size_t)32768 * 2);

  k_prep<<<1600, 256, 0, stream>>>(wq, wk, wv, wd, wo, desc, wqT, wkT, wvT, wdT, woT, descb);
  k_convln<<<512, 256, 0, stream>>>(vox, cw, cb, lng, lnb, pos, vox_emb);
  k_des<<<256, 64, 0, stream>>>(descb, wdT, bd, desemb);
  k_kvproj<<<dim3(256, 2), 64, 0, stream>>>(desemb, wkT, bk, wvT, bv, kb, ek, vtb);
  k_attn<<<dim3(16, 32), 256, 0, stream>>>(vox_emb, wqT, bq, alpha, kb, ek, vtb, attn);
  k_out<<<1024, 64, 0, stream>>>(attn, woT, bo, out);
}

// Round 5
// 134.834 us; speedup vs baseline: 1.4297x; 1.1977x over previous
//
#include <hip/hip_runtime.h>

typedef unsigned short u16;
typedef __bf16 bf16x8 __attribute__((ext_vector_type(8)));
typedef float f32x4 __attribute__((ext_vector_type(4)));

struct alignas(16) V4 { unsigned x, y, z, w; };
struct alignas(8)  V2 { unsigned x, y; };

// f32 -> bf16 RTNE (bit-twiddle; HW-verified in R1/R4)
__device__ __forceinline__ u16 f2b(float f) {
  unsigned u = __builtin_bit_cast(unsigned, f);
  u += 0x7FFFu + ((u >> 16) & 1u);
  return (u16)(u >> 16);
}
// RTNE pack of two f32 -> u32 (lo = a, hi = b)
__device__ __forceinline__ unsigned pk2(float a, float b) {
  return (unsigned)f2b(a) | ((unsigned)f2b(b) << 16);
}
__device__ __forceinline__ bf16x8 asb(V4 v) { return __builtin_bit_cast(bf16x8, v); }
__device__ __forceinline__ bf16x8 mk8(unsigned a, unsigned b, unsigned c, unsigned d) {
  V4 v; v.x = a; v.y = b; v.z = c; v.w = d; return asb(v);
}
__device__ __forceinline__ V4 ldg16(const u16* p) { return *reinterpret_cast<const V4*>(p); }
__device__ __forceinline__ f32x4 mfma16(bf16x8 a, bf16x8 b, f32x4 c) {
  return __builtin_amdgcn_mfma_f32_16x16x32_bf16(a, b, c, 0, 0, 0);
}
// LDS fragment, split k-map: 8B at base+off, 8B at base+off+32.
// Valid because the same (lane,reg)->k assignment is used on both operands.
__device__ __forceinline__ bf16x8 ldfrag(const char* base, int off) {
  V2 lo = *reinterpret_cast<const V2*>(base + off);
  V2 hi = *reinterpret_cast<const V2*>(base + off + 32);
  return mk8(lo.x, lo.y, hi.x, hi.y);
}

// ---------------------------------------------------------------------------
// Prep: transpose+cast weights to bf16, cast descriptor to bf16.
// ---------------------------------------------------------------------------
__global__ __launch_bounds__(256) void k_prep(
    const float* __restrict__ wq, const float* __restrict__ wk,
    const float* __restrict__ wv, const float* __restrict__ wd,
    const float* __restrict__ wo, const float* __restrict__ desc,
    u16* __restrict__ wqT, u16* __restrict__ wkT, u16* __restrict__ wvT,
    u16* __restrict__ wdT, u16* __restrict__ woT, u16* __restrict__ descb) {
  int i = blockIdx.x * 256 + threadIdx.x;
  if (i < 32768) {                                   // wqT[n][d] = wq[d][n]
    int n = i >> 6, d = i & 63;
    wqT[i] = f2b(wq[d * 512 + n]);
  } else if (i < 65536) {
    int j = i - 32768; int n = j >> 6, d = j & 63;
    wkT[j] = f2b(wk[d * 512 + n]);
  } else if (i < 98304) {
    int j = i - 65536; int n = j >> 6, d = j & 63;
    wvT[j] = f2b(wv[d * 512 + n]);
  } else if (i < 114688) {                           // wdT[e][v] = wd[v][e]
    int j = i - 98304; int e = j >> 8, v = j & 255;
    wdT[j] = f2b(wd[v * 64 + e]);
  } else if (i < 147456) {                           // woT[n][k] = wo[k][n]
    int j = i - 114688; int n = j >> 9, kk = j & 511;
    woT[j] = f2b(wo[kk * 64 + n]);
  } else if (i < 409600) {                           // descb, 4 elems/thread
    int j = (i - 147456) * 4;
    const f32x4 dv = *reinterpret_cast<const f32x4*>(desc + j);
    uint2 pw; pw.x = pk2(dv[0], dv[1]); pw.y = pk2(dv[2], dv[3]);
    *reinterpret_cast<uint2*>(descb + j) = pw;
  }
}

// ---------------------------------------------------------------------------
// Conv3d(P=4,stride=4) + LayerNorm + pos_emb -> vox_emb bf16 [16384][64]
// ---------------------------------------------------------------------------
__global__ __launch_bounds__(256) void k_convln(
    const float* __restrict__ vox, const float* __restrict__ cw,
    const float* __restrict__ cb, const float* __restrict__ lng,
    const float* __restrict__ lnb, const float* __restrict__ pos,
    u16* __restrict__ vox_emb) {
  __shared__ float wT[64 * 65];
  __shared__ float pl[4][64];
  const int t = threadIdx.x;
  for (int i = t; i < 4096; i += 256) wT[(i & 63) * 65 + (i >> 6)] = cw[i];
  const int w = t >> 6, lane = t & 63;
  const float cbl = cb[lane], lg = lng[lane], lb = lnb[lane];
  const int i3 = lane >> 4, j3 = (lane >> 2) & 3, k3 = lane & 3;
  for (int i = 0; i < 8; ++i) {
    const int row = blockIdx.x * 32 + w * 8 + i;
    const int b = row >> 12, np = row & 4095;
    const int pd = np >> 8, ph = (np >> 4) & 15, pw = np & 15;
    __syncthreads();
    pl[w][lane] = vox[(size_t)b * 262144 + (size_t)(pd * 4 + i3) * 4096 +
                      (ph * 4 + j3) * 64 + (pw * 4 + k3)];
    __syncthreads();
    float acc = cbl;
    #pragma unroll
    for (int v = 0; v < 64; ++v) acc += pl[w][v] * wT[v * 65 + lane];
    float s1 = acc, s2 = acc * acc;
    #pragma unroll
    for (int m = 1; m < 64; m <<= 1) { s1 += __shfl_xor(s1, m); s2 += __shfl_xor(s2, m); }
    const float mu = s1 * (1.0f / 64.0f);
    const float var = s2 * (1.0f / 64.0f) - mu * mu;
    const float y = (acc - mu) * rsqrtf(var + 1e-5f) * lg + lb + pos[np * 64 + lane];
    vox_emb[(size_t)row * 64 + lane] = f2b(y);
  }
}

// ---------------------------------------------------------------------------
// des_emb = descb[4096][256] @ wd + bd -> bf16 [4096][64]
// ---------------------------------------------------------------------------
__global__ __launch_bounds__(64) void k_des(
    const u16* __restrict__ descb, const u16* __restrict__ wdT,
    const float* __restrict__ bd, u16* __restrict__ desemb) {
  const int lane = threadIdx.x, lr = lane & 15, lc = lane >> 4;
  const int sd0 = blockIdx.x * 16;
  bf16x8 db[8];
  #pragma unroll
  for (int kc = 0; kc < 8; ++kc)
    db[kc] = asb(ldg16(descb + (size_t)(sd0 + lr) * 256 + kc * 32 + lc * 8));
  #pragma unroll
  for (int et = 0; et < 4; ++et) {
    f32x4 acc = {0.f, 0.f, 0.f, 0.f};
    #pragma unroll
    for (int kc = 0; kc < 8; ++kc) {
      const bf16x8 wa = asb(ldg16(wdT + (size_t)(et * 16 + lr) * 256 + kc * 32 + lc * 8));
      acc = mfma16(wa, db[kc], acc);
    }
    const f32x4 bdv = *reinterpret_cast<const f32x4*>(bd + et * 16 + lc * 4);
    uint2 pw;
    pw.x = pk2(acc[0] + bdv[0], acc[1] + bdv[1]);
    pw.y = pk2(acc[2] + bdv[2], acc[3] + bdv[3]);
    *reinterpret_cast<uint2*>(desemb + (size_t)(sd0 + lr) * 64 + et * 16 + lc * 4) = pw;
  }
}

// ---------------------------------------------------------------------------
// K/V projections. kb bf16 [bh][1024][64]; ek = exp(-|k|^2) f32;
// vtb bf16 transposed [bh][64][1024].
// ---------------------------------------------------------------------------
__global__ __launch_bounds__(64) void k_kvproj(
    const u16* __restrict__ desemb, const u16* __restrict__ wkT,
    const float* __restrict__ bk, const u16* __restrict__ wvT,
    const float* __restrict__ bv, u16* __restrict__ kb,
    float* __restrict__ ek, u16* __restrict__ vtb) {
  const int lane = threadIdx.x, lr = lane & 15, lc = lane >> 4;
  const int x = blockIdx.x, half = blockIdx.y;
  const int b = x >> 6, sd0 = (x & 63) * 16;
  const u16* drow = desemb + (size_t)(x * 16 + lr) * 64;
  const bf16x8 da0 = asb(ldg16(drow + lc * 8));
  const bf16x8 da1 = asb(ldg16(drow + 32 + lc * 8));
  float sq = 0.f;
  #pragma unroll
  for (int et = 0; et < 16; ++et) {                 // K pass (flipped)
    const int etg = half * 16 + et;
    const u16* wrow = wkT + (size_t)(etg * 16 + lr) * 64;
    f32x4 acc = {0.f, 0.f, 0.f, 0.f};
    acc = mfma16(asb(ldg16(wrow + lc * 8)), da0, acc);
    acc = mfma16(asb(ldg16(wrow + 32 + lc * 8)), da1, acc);
    const f32x4 bkv = *reinterpret_cast<const f32x4*>(bk + etg * 16 + lc * 4);
    const float k0 = acc[0] + bkv[0], k1 = acc[1] + bkv[1];
    const float k2 = acc[2] + bkv[2], k3 = acc[3] + bkv[3];
    sq += k0 * k0 + k1 * k1 + k2 * k2 + k3 * k3;
    const int h = etg >> 2;
    uint2 pw; pw.x = pk2(k0, k1); pw.y = pk2(k2, k3);
    *reinterpret_cast<uint2*>(kb + ((size_t)(b * 8 + h) * 1024 + sd0 + lr) * 64 +
                              (etg & 3) * 16 + lc * 4) = pw;
    if ((etg & 3) == 3) {
      float s = sq;
      s += __shfl_xor(s, 16); s += __shfl_xor(s, 32);
      if (lc == 0) ek[(size_t)(b * 8 + h) * 1024 + sd0 + lr] = __expf(-s);
      sq = 0.f;
    }
  }
  #pragma unroll
  for (int et = 0; et < 16; ++et) {                 // V pass
    const int etg = half * 16 + et;
    const u16* wrow = wvT + (size_t)(etg * 16 + lr) * 64;
    f32x4 acc = {0.f, 0.f, 0.f, 0.f};
    acc = mfma16(da0, asb(ldg16(wrow + lc * 8)), acc);
    acc = mfma16(da1, asb(ldg16(wrow + 32 + lc * 8)), acc);
    const float bvs = bv[etg * 16 + lr];
    const int h = etg >> 2;
    uint2 pw;
    pw.x = pk2(acc[0] + bvs, acc[1] + bvs);
    pw.y = pk2(acc[2] + bvs, acc[3] + bvs);
    *reinterpret_cast<uint2*>(vtb + ((size_t)(b * 8 + h) * 64 + (etg & 3) * 16 + lr) * 1024 +
                              sd0 + lc * 4) = pw;
  }
}

// ---------------------------------------------------------------------------
// Fused Q-projection + L2 attention. R4-exact arithmetic (proven).
// R5 change: 32 q-rows/wave (2 groups), grid (32, 32) = 1024 blocks
// -> 4 blocks/CU (LDS-limited), 16 waves/CU, ~4x occupancy vs R4.
// ---------------------------------------------------------------------------
__global__ __launch_bounds__(256, 4) void k_attn(
    const u16* __restrict__ vox_emb, const u16* __restrict__ wqT,
    const float* __restrict__ bq, const float* __restrict__ alpha,
    const u16* __restrict__ kb, const float* __restrict__ ekg,
    const u16* __restrict__ vtb, u16* __restrict__ attn) {
  __shared__ __align__(16) char Kl[128 * 144];   // K tile: 128 x 64 bf16, 144B stride
  __shared__ __align__(16) char Vl[64 * 272];    // V^T tile: 64 x 128 bf16, 272B stride
  const int t = threadIdx.x, w = t >> 6, lane = t & 63, lr = lane & 15, lc = lane >> 4;
  const int bh = blockIdx.y, b = bh >> 3, h = bh & 7;
  const int q0 = blockIdx.x * 128 + w * 32;   // this wave's 32 q rows

  // ---- Q: q = vox_emb @ wq + bq; fragments hold f2b(q) (unscaled, R4-exact)
  bf16x8 qf0[2], qf1[2];
  float av[2];
  {
    bf16x8 vb0[2], vb1[2];
    #pragma unroll
    for (int g = 0; g < 2; ++g) {
      const u16* vrow = vox_emb + (size_t)(b * 4096 + q0 + g * 16 + lr) * 64;
      vb0[g] = asb(ldg16(vrow + lc * 8));
      vb1[g] = asb(ldg16(vrow + 32 + lc * 8));
    }
    float sq[2] = {0.f, 0.f};
    unsigned qd[2][4][2];
    #pragma unroll
    for (int et = 0; et < 4; ++et) {
      const u16* wrow = wqT + (size_t)((h * 4 + et) * 16 + lr) * 64;
      const bf16x8 wa0 = asb(ldg16(wrow + lc * 8));
      const bf16x8 wa1 = asb(ldg16(wrow + 32 + lc * 8));
      const f32x4 bqv = *reinterpret_cast<const f32x4*>(bq + (h * 4 + et) * 16 + lc * 4);
      #pragma unroll
      for (int g = 0; g < 2; ++g) {
        f32x4 acc = {0.f, 0.f, 0.f, 0.f};
        acc = mfma16(wa0, vb0[g], acc);
        acc = mfma16(wa1, vb1[g], acc);
        const float v0 = acc[0] + bqv[0], v1 = acc[1] + bqv[1];
        const float v2 = acc[2] + bqv[2], v3 = acc[3] + bqv[3];
        sq[g] += v0 * v0 + v1 * v1 + v2 * v2 + v3 * v3;
        qd[g][et][0] = pk2(v0, v1);
        qd[g][et][1] = pk2(v2, v3);
      }
    }
    const float ca = 0.125f * alpha[0];
    #pragma unroll
    for (int g = 0; g < 2; ++g) {
      float s = sq[g];
      s += __shfl_xor(s, 16); s += __shfl_xor(s, 32);
      av[g] = ca * __expf(-s);      // alpha*SCALE*exp(-|q|^2), fp32 q
      qf0[g] = mk8(qd[g][0][0], qd[g][0][1], qd[g][1][0], qd[g][1][1]);
      qf1[g] = mk8(qd[g][2][0], qd[g][2][1], qd[g][3][0], qd[g][3][1]);
    }
  }

  const f32x4 z = {0.f, 0.f, 0.f, 0.f};
  f32x4 o[2][4];
  float dn[2] = {0.f, 0.f};
  #pragma unroll
  for (int g = 0; g < 2; ++g)
    #pragma unroll
    for (int m = 0; m < 4; ++m) o[g][m] = z;

  const V4* kb4 = reinterpret_cast<const V4*>(kb) + (size_t)bh * 1024 * 8;
  const V4* vt4 = reinterpret_cast<const V4*>(vtb) + (size_t)bh * 64 * 128;
  const float* ekh = ekg + (size_t)bh * 1024;

  for (int kt = 0; kt < 8; ++kt) {
    {  // stage K (128x64) and V^T (64x128) tiles
      const int rk = t >> 1, hk = (t & 1) * 4;
      const V4* ks = kb4 + (size_t)(kt * 128 + rk) * 8 + hk;
      V4* kd = reinterpret_cast<V4*>(Kl + rk * 144 + hk * 16);
      kd[0] = ks[0]; kd[1] = ks[1]; kd[2] = ks[2]; kd[3] = ks[3];
      const int re = t >> 2, hv = (t & 3) * 4;
      const V4* vs = vt4 + (size_t)re * 128 + kt * 16 + hv;
      V4* vd = reinterpret_cast<V4*>(Vl + re * 272 + hv * 16);
      vd[0] = vs[0]; vd[1] = vs[1]; vd[2] = vs[2]; vd[3] = vs[3];
    }
    __syncthreads();
    #pragma unroll
    for (int c2 = 0; c2 < 4; ++c2) {
      const char* kr0 = Kl + (c2 * 32 + lr) * 144 + lc * 8;
      const char* kr1 = kr0 + 16 * 144;
      const bf16x8 ka00 = ldfrag(kr0, 0),  ka01 = ldfrag(kr0, 64);
      const bf16x8 ka10 = ldfrag(kr1, 0),  ka11 = ldfrag(kr1, 64);
      const char* vrb = Vl + lr * 272 + c2 * 64 + lc * 8;
      const bf16x8 va0 = ldfrag(vrb, 0);
      const bf16x8 va1 = ldfrag(vrb + 16 * 272, 0);
      const bf16x8 va2 = ldfrag(vrb + 32 * 272, 0);
      const bf16x8 va3 = ldfrag(vrb + 48 * 272, 0);
      const f32x4 e0v = *reinterpret_cast<const f32x4*>(ekh + kt * 128 + c2 * 32 + lc * 4);
      const f32x4 e1v = *reinterpret_cast<const f32x4*>(ekh + kt * 128 + c2 * 32 + 16 + lc * 4);
      #pragma unroll
      for (int g = 0; g < 2; ++g) {
        f32x4 s0 = z, s1 = z;
        s0 = mfma16(ka00, qf0[g], s0); s0 = mfma16(ka01, qf1[g], s0);
        s1 = mfma16(ka10, qf0[g], s1); s1 = mfma16(ka11, qf1[g], s1);
        // R4-exact: p = expf(aeq * ek * expf(2*q.k))
        const float p00 = __expf(av[g] * e0v[0] * __expf(2.0f * s0[0]));
        const float p01 = __expf(av[g] * e0v[1] * __expf(2.0f * s0[1]));
        const float p02 = __expf(av[g] * e0v[2] * __expf(2.0f * s0[2]));
        const float p03 = __expf(av[g] * e0v[3] * __expf(2.0f * s0[3]));
        const float p10 = __expf(av[g] * e1v[0] * __expf(2.0f * s1[0]));
        const float p11 = __expf(av[g] * e1v[1] * __expf(2.0f * s1[1]));
        const float p12 = __expf(av[g] * e1v[2] * __expf(2.0f * s1[2]));
        const float p13 = __expf(av[g] * e1v[3] * __expf(2.0f * s1[3]));
        dn[g] += ((p00 + p01) + (p02 + p03)) + ((p10 + p11) + (p12 + p13));
        const bf16x8 pf = mk8(pk2(p00, p01), pk2(p02, p03),
                              pk2(p10, p11), pk2(p12, p13));
        o[g][0] = mfma16(va0, pf, o[g][0]);
        o[g][1] = mfma16(va1, pf, o[g][1]);
        o[g][2] = mfma16(va2, pf, o[g][2]);
        o[g][3] = mfma16(va3, pf, o[g][3]);
      }
    }
    __syncthreads();
  }

  u16* obase = attn + (size_t)(b * 4096 + q0 + lr) * 512 + h * 64 + lc * 4;
  #pragma unroll
  for (int g = 0; g < 2; ++g) {
    float s = dn[g];
    s += __shfl_xor(s, 16); s += __shfl_xor(s, 32);   // sum lane's k-subsets over lc
    const float inv = 1.0f / s;
    #pragma unroll
    for (int m = 0; m < 4; ++m) {
      uint2 pw;
      pw.x = pk2(o[g][m][0] * inv, o[g][m][1] * inv);
      pw.y = pk2(o[g][m][2] * inv, o[g][m][3] * inv);
      *reinterpret_cast<uint2*>(obase + (size_t)g * 16 * 512 + m * 16) = pw;
    }
  }
}

// ---------------------------------------------------------------------------
// out = attn[16384][512] @ wo + bo -> fp32 [16384][64]
// ---------------------------------------------------------------------------
__global__ __launch_bounds__(64) void k_out(
    const u16* __restrict__ attn, const u16* __restrict__ woT,
    const float* __restrict__ bo, float* __restrict__ out) {
  const int lane = threadIdx.x, lr = lane & 15, lc = lane >> 4;
  const int np0 = blockIdx.x * 16;
  const u16* arow = attn + (size_t)(np0 + lr) * 512;
  f32x4 acc[4] = {{0.f,0.f,0.f,0.f},{0.f,0.f,0.f,0.f},{0.f,0.f,0.f,0.f},{0.f,0.f,0.f,0.f}};
  #pragma unroll
  for (int kc = 0; kc < 16; ++kc) {
    const bf16x8 bfr = asb(ldg16(arow + kc * 32 + lc * 8));
    #pragma unroll
    for (int et = 0; et < 4; ++et) {
      const bf16x8 wa = asb(ldg16(woT + (size_t)(et * 16 + lr) * 512 + kc * 32 + lc * 8));
      acc[et] = mfma16(wa, bfr, acc[et]);
    }
  }
  #pragma unroll
  for (int et = 0; et < 4; ++et) {
    const f32x4 bov = *reinterpret_cast<const f32x4*>(bo + et * 16 + lc * 4);
    const f32x4 r = acc[et] + bov;
    *reinterpret_cast<f32x4*>(out + (size_t)(np0 + lr) * 64 + et * 16 + lc * 4) = r;
  }
}

// ---------------------------------------------------------------------------
extern "C" void kernel_launch(void* const* d_in, const int* in_sizes, int n_in,
                              void* d_out, int out_size, void* d_ws, size_t ws_size,
                              hipStream_t stream) {
  (void)in_sizes; (void)n_in; (void)out_size; (void)ws_size;
  const float* vox   = (const float*)d_in[0];
  const float* desc  = (const float*)d_in[1];
  const float* cw    = (const float*)d_in[2];
  const float* cb    = (const float*)d_in[3];
  const float* lng   = (const float*)d_in[4];
  const float* lnb   = (const float*)d_in[5];
  const float* pos   = (const float*)d_in[6];
  const float* wq    = (const float*)d_in[7];
  const float* bq    = (const float*)d_in[8];
  const float* wk    = (const float*)d_in[9];
  const float* bk    = (const float*)d_in[10];
  const float* wv    = (const float*)d_in[11];
  const float* bv    = (const float*)d_in[12];
  const float* wd    = (const float*)d_in[13];
  const float* bd    = (const float*)d_in[14];
  const float* alpha = (const float*)d_in[15];
  const float* wo    = (const float*)d_in[16];
  const float* bo    = (const float*)d_in[17];
  float* out = (float*)d_out;

  char* ws = (char*)d_ws;
  size_t off = 0;
  auto alloc = [&](size_t bytes) {
    char* p = ws + off;
    off += (bytes + 255) & ~(size_t)255;
    return p;
  };
  u16*   vox_emb = (u16*)alloc((size_t)16384 * 64 * 2);
  u16*   descb   = (u16*)alloc((size_t)4096 * 256 * 2);
  u16*   desemb  = (u16*)alloc((size_t)4096 * 64 * 2);
  u16*   kb      = (u16*)alloc((size_t)4096 * 512 * 2);
  u16*   vtb     = (u16*)alloc((size_t)4096 * 512 * 2);
  float* ek      = (float*)alloc((size_t)32768 * 4);
  u16*   attn    = (u16*)alloc((size_t)16384 * 512 * 2);
  u16*   wqT     = (u16*)alloc((size_t)32768 * 2);
  u16*   wkT     = (u16*)alloc((size_t)32768 * 2);
  u16*   wvT     = (u16*)alloc((size_t)32768 * 2);
  u16*   wdT     = (u16*)alloc((size_t)16384 * 2);
  u16*   woT     = (u16*)alloc((size_t)32768 * 2);

  k_prep<<<1600, 256, 0, stream>>>(wq, wk, wv, wd, wo, desc, wqT, wkT, wvT, wdT, woT, descb);
  k_convln<<<512, 256, 0, stream>>>(vox, cw, cb, lng, lnb, pos, vox_emb);
  k_des<<<256, 64, 0, stream>>>(descb, wdT, bd, desemb);
  k_kvproj<<<dim3(256, 2), 64, 0, stream>>>(desemb, wkT, bk, wvT, bv, kb, ek, vtb);
  k_attn<<<dim3(32, 32), 256, 0, stream>>>(vox_emb, wqT, bq, alpha, kb, ek, vtb, attn);
  k_out<<<1024, 64, 0, stream>>>(attn, woT, bo, out);
}